// Round 5
// baseline (257.917 us; speedup 1.0000x reference)
//
#include <hip/hip_runtime.h>
#include <hip/hip_fp16.h>

// GridEncoder (instant-NGP triplane hash grid), static config:
//   D=3, L=3, C=2, base_res=128, per_level_scale=2, hashmap=2^19,
//   align_corners=False, linear interp, B=2^21.
// All levels hash-index; hmap=2^19 -> mod == & 0x7FFFF.
// emb[idx][c] == triplane_flat[l*2^20 + c*2^19 + (idx & 0x7FFFF)].
//
// R1: naive fp32 -> 543 us (HBM-bound, FETCH 1.97 GB).
// R2: half2 table + 3 level passes -> 254 us (62 us/pass, req-rate bound).
// R4: fused single kernel -> 250 us (gather 175 us; 287 G req/s == same
//     request-rate ceiling as R2; VALUBusy 8%, cache residency irrelevant).
// R5: GRAY-CODED table layout. Hash pairs along x differ by d=gx^(gx+1);
//     in Gray layout positions differ by Gray(d)=2^k, so one aligned 16B
//     quad covers both x-corners for 3/4 of cases -> 24 -> ~15 requests
//     per point (-37%). Extraction = cndmask selects (VALU has headroom).

#define NPOINTS  2097152
#define HMASK    0x7FFFFu
#define PLANE    524288            // entries per level table
#define NTAB     (3 * PLANE)       // packed half2 entries (6 MB)

typedef float    floatx2 __attribute__((ext_vector_type(2)));
typedef unsigned uintx4  __attribute__((ext_vector_type(4)));

// ---- prepass: tbl[level, Gray(h)] = half2(b[h], b[PLANE+h]) ----
// coalesced reads of the fp32 planes, scattered (bijective) writes
__global__ __launch_bounds__(256) void tp_convert_kernel(
    const float* __restrict__ tp, unsigned* __restrict__ tbl)
{
    const unsigned t = blockIdx.x * 256u + threadIdx.x;   // < NTAB
    const unsigned level = t >> 19;
    const unsigned h     = t & HMASK;
    const float* __restrict__ b = tp + level * (2u * PLANE);
    const __half2 h2 = __halves2half2(__float2half_rn(b[h]),
                                      __float2half_rn(b[PLANE + h]));
    const unsigned pos = h ^ (h >> 1);                    // Gray(h) < 2^19
    tbl[(level << 19) | pos] = *reinterpret_cast<const unsigned*>(&h2);
}

// select element o (0..3) of a quad: 3 cndmasks
__device__ __forceinline__ unsigned sel4(uintx4 q, unsigned o) {
    const unsigned a = (o & 1u) ? q.y : q.x;
    const unsigned b = (o & 1u) ? q.w : q.z;
    return (o & 2u) ? b : a;
}

// ---- fused gather over the Gray-coded table ----
__global__ __launch_bounds__(256) void grid_gather_kernel(
    const unsigned* __restrict__ tbl,
    const float* __restrict__ inputs,
    floatx2* __restrict__ out)
{
    const int i = blockIdx.x * 256 + threadIdx.x;

    const float x = __builtin_nontemporal_load(&inputs[3 * i + 0]);
    const float y = __builtin_nontemporal_load(&inputs[3 * i + 1]);
    const float z = __builtin_nontemporal_load(&inputs[3 * i + 2]);
    const float x0 = (x + 1.0f) * 0.5f;
    const float y0 = (y + 1.0f) * 0.5f;
    const float z0 = (z + 1.0f) * 0.5f;

    unsigned P0[12];        // full table position of each bx=0 corner
    unsigned gbits[3];      // Gray(gx ^ (gx+1)) per level
    float rxs[3], rys[3], rzs[3];

#pragma unroll
    for (int level = 0; level < 3; ++level) {
        const float scale = (float)((128 << level) - 1);  // 127, 255, 511
        const float px = fmaf(x0, scale, 0.5f);
        const float py = fmaf(y0, scale, 0.5f);
        const float pz = fmaf(z0, scale, 0.5f);
        const float fx = floorf(px), fy = floorf(py), fz = floorf(pz);
        rxs[level] = px - fx; rys[level] = py - fy; rzs[level] = pz - fz;
        const unsigned gx = (unsigned)fx, gy = (unsigned)fy, gz = (unsigned)fz;

        const unsigned d = gx ^ (gx + 1u);
        gbits[level] = d ^ (d >> 1);                      // Gray(d) = 2^k

        const unsigned hy0 = gy * 2654435761u;
        const unsigned hy1 = (gy + 1u) * 2654435761u;
        const unsigned hz0 = gz * 805459861u;
        const unsigned hz1 = (gz + 1u) * 805459861u;
        const unsigned lvl = (unsigned)level << 19;

        // bx=0 corner hashes for the 4 (y,z) combos; Gray position
        const unsigned h0 = (gx ^ hy0 ^ hz0) & HMASK;
        const unsigned h1 = (gx ^ hy1 ^ hz0) & HMASK;
        const unsigned h2 = (gx ^ hy0 ^ hz1) & HMASK;
        const unsigned h3 = (gx ^ hy1 ^ hz1) & HMASK;
        P0[level * 4 + 0] = lvl | (h0 ^ (h0 >> 1));
        P0[level * 4 + 1] = lvl | (h1 ^ (h1 >> 1));
        P0[level * 4 + 2] = lvl | (h2 ^ (h2 >> 1));
        P0[level * 4 + 3] = lvl | (h3 ^ (h3 >> 1));
    }

    // issue all 12 unconditional quad loads up front (max MLP)
    uintx4 Q[12];
#pragma unroll
    for (int k = 0; k < 12; ++k)
        Q[k] = *reinterpret_cast<const uintx4*>(tbl + (P0[k] & ~3u));

    float o0 = 0.0f, o1 = 0.0f;
#pragma unroll
    for (int level = 0; level < 3; ++level) {
        const unsigned g = gbits[level];
        const bool two = g >= 4u;    // partner outside the quad (gx%4 == 3)

        uintx4 Q2[4];
#pragma unroll
        for (int j = 0; j < 4; ++j) Q2[j] = Q[level * 4 + j];
        if (two) {
#pragma unroll
            for (int j = 0; j < 4; ++j)
                Q2[j] = *reinterpret_cast<const uintx4*>(
                    tbl + ((P0[level * 4 + j] ^ g) & ~3u));
        }

        const float rx = rxs[level], ry = rys[level], rz = rzs[level];
        const float wx1 = rx, wx0 = 1.0f - rx;
        const float wy1 = ry, wy0 = 1.0f - ry;
        const float wz1 = rz, wz0 = 1.0f - rz;
        const float wyz[4] = { wy0 * wz0, wy1 * wz0, wy0 * wz1, wy1 * wz1 };

#pragma unroll
        for (int j = 0; j < 4; ++j) {
            const unsigned off0 = P0[level * 4 + j] & 3u;
            const unsigned e0 = sel4(Q[level * 4 + j], off0);
            const unsigned e1 = sel4(Q2[j], off0 ^ (g & 3u));
            const __half2 a = *reinterpret_cast<const __half2*>(&e0);
            const __half2 b = *reinterpret_cast<const __half2*>(&e1);
            const float2 fa = __half22float2(a);
            const float2 fb = __half22float2(b);
            const float wA = wx0 * wyz[j], wB = wx1 * wyz[j];
            o0 = fmaf(wA, fa.x, o0); o1 = fmaf(wA, fa.y, o1);
            o0 = fmaf(wB, fb.x, o0); o1 = fmaf(wB, fb.y, o1);
        }
    }

    floatx2 r; r.x = o0; r.y = o1;
    __builtin_nontemporal_store(r, &out[i]);
}

// ---- fallback (R1 kernel) if ws_size is too small for the packed table ----
__global__ __launch_bounds__(256) void grid_fallback_kernel(
    const float* __restrict__ triplane,
    const float* __restrict__ inputs,
    float* __restrict__ out)
{
    const int i = blockIdx.x * blockDim.x + threadIdx.x;
    if (i >= NPOINTS) return;
    const float x0 = (inputs[3 * i + 0] + 1.0f) * 0.5f;
    const float y0 = (inputs[3 * i + 1] + 1.0f) * 0.5f;
    const float z0 = (inputs[3 * i + 2] + 1.0f) * 0.5f;
    float o0 = 0.0f, o1 = 0.0f;
#pragma unroll
    for (int level = 0; level < 3; ++level) {
        const float scale = (float)((128 << level) - 1);
        const float px = fmaf(x0, scale, 0.5f);
        const float py = fmaf(y0, scale, 0.5f);
        const float pz = fmaf(z0, scale, 0.5f);
        const float fx = floorf(px), fy = floorf(py), fz = floorf(pz);
        const float rx = px - fx, ry = py - fy, rz = pz - fz;
        const unsigned gx = (unsigned)fx, gy = (unsigned)fy, gz = (unsigned)fz;
        const float* __restrict__ base = triplane + level * (2 * PLANE);
#pragma unroll
        for (int c = 0; c < 8; ++c) {
            const unsigned bx = (c >> 0) & 1, by = (c >> 1) & 1, bz = (c >> 2) & 1;
            const unsigned h = (gx + bx) ^ ((gy + by) * 2654435761u) ^ ((gz + bz) * 805459861u);
            const unsigned local = h & HMASK;
            const float w = (bx ? rx : 1.0f - rx) * (by ? ry : 1.0f - ry) * (bz ? rz : 1.0f - rz);
            o0 = fmaf(w, base[local], o0);
            o1 = fmaf(w, base[PLANE + local], o1);
        }
    }
    reinterpret_cast<float2*>(out)[i] = make_float2(o0, o1);
}

extern "C" void kernel_launch(void* const* d_in, const int* in_sizes, int n_in,
                              void* d_out, int out_size, void* d_ws, size_t ws_size,
                              hipStream_t stream) {
    const float* triplane = (const float*)d_in[0];  // 3*2*1024*512 fp32
    const float* inputs   = (const float*)d_in[1];  // B*3 fp32
    const int threads = 256;
    const int gblocks = NPOINTS / threads;          // 8192

    if (ws_size >= (size_t)NTAB * sizeof(unsigned)) {
        unsigned* tbl = (unsigned*)d_ws;
        tp_convert_kernel<<<NTAB / threads, threads, 0, stream>>>(triplane, tbl);
        grid_gather_kernel<<<gblocks, threads, 0, stream>>>(tbl, inputs, (floatx2*)d_out);
    } else {
        grid_fallback_kernel<<<gblocks, threads, 0, stream>>>(triplane, inputs, (float*)d_out);
    }
}

// Round 6
// 231.444 us; speedup vs baseline: 1.1144x; 1.1144x over previous
//
#include <hip/hip_runtime.h>
#include <hip/hip_fp16.h>

// GridEncoder (instant-NGP triplane hash grid), static config:
//   D=3, L=3, C=2, base_res=128, per_level_scale=2, hashmap=2^19,
//   align_corners=False, linear interp, B=2^21.
// All levels hash-index; hmap=2^19 -> mod == & 0x7FFFF.
//
// R1: naive fp32 -> 543 us (HBM-bound, FETCH 1.97 GB).
// R2: half2 table + 3 level passes -> 254 us (62 us/pass).
// R4: fused, 24x 4B gathers -> gather 175 us (287 G req/s).
// R5: all-16B Gray quads, 15 req/pt -> 184 us. SLOWER: request-only model
//     falsified. Fit: cost/lane-request ~= 1.65 cyc + 0.12 cyc/byte
//     (R4: 2.14, R5: 3.61 cyc/req — both match measured within 5%).
// R6: MIXED-WIDTH Gray loads — narrowest load covering each x-pair:
//     g==1 (p=1/2): one 8B ; g==2 (p=1/4): one 16B ; g>=4: two 4B.
//     3.29 cyc/pair avg -> ~40 cyc/pt (vs 51/54). Bytes/pt 240->120.

#define NPOINTS  2097152
#define HMASK    0x7FFFFu
#define PLANE    524288            // entries per level table
#define NTAB     (3 * PLANE)       // packed half2 entries (6 MB)

typedef float    floatx2 __attribute__((ext_vector_type(2)));
typedef unsigned uintx2  __attribute__((ext_vector_type(2)));
typedef unsigned uintx4  __attribute__((ext_vector_type(4)));

// ---- prepass: tbl[level, Gray(h)] = half2(b[h], b[PLANE+h]) ----
// Gray scatter stays within aligned 64-entry windows -> writes still coalesce.
__global__ __launch_bounds__(256) void tp_convert_kernel(
    const float* __restrict__ tp, unsigned* __restrict__ tbl)
{
    const unsigned t = blockIdx.x * 256u + threadIdx.x;   // < NTAB
    const unsigned level = t >> 19;
    const unsigned h     = t & HMASK;
    const float* __restrict__ b = tp + level * (2u * PLANE);
    const __half2 h2 = __halves2half2(__float2half_rn(b[h]),
                                      __float2half_rn(b[PLANE + h]));
    const unsigned pos = h ^ (h >> 1);                    // Gray(h) < 2^19
    tbl[(level << 19) | pos] = *reinterpret_cast<const unsigned*>(&h2);
}

__device__ __forceinline__ unsigned sel4(uintx4 q, unsigned o) {
    const unsigned a = (o & 1u) ? q.y : q.x;
    const unsigned b = (o & 1u) ? q.w : q.z;
    return (o & 2u) ? b : a;
}

// ---- fused gather, mixed-width Gray pair loads ----
__global__ __launch_bounds__(256) void grid_gather_kernel(
    const unsigned* __restrict__ tbl,
    const float* __restrict__ inputs,
    floatx2* __restrict__ out)
{
    const int i = blockIdx.x * 256 + threadIdx.x;

    const float x = __builtin_nontemporal_load(&inputs[3 * i + 0]);
    const float y = __builtin_nontemporal_load(&inputs[3 * i + 1]);
    const float z = __builtin_nontemporal_load(&inputs[3 * i + 2]);
    const float x0 = (x + 1.0f) * 0.5f;
    const float y0 = (y + 1.0f) * 0.5f;
    const float z0 = (z + 1.0f) * 0.5f;

    unsigned P0[12];        // lvl | Gray position of each bx=0 corner
    unsigned gbits[3];      // Gray(gx ^ (gx+1)) = 2^k, per level
    float rxs[3], rys[3], rzs[3];

#pragma unroll
    for (int level = 0; level < 3; ++level) {
        const float scale = (float)((128 << level) - 1);  // 127, 255, 511
        const float px = fmaf(x0, scale, 0.5f);
        const float py = fmaf(y0, scale, 0.5f);
        const float pz = fmaf(z0, scale, 0.5f);
        const float fx = floorf(px), fy = floorf(py), fz = floorf(pz);
        rxs[level] = px - fx; rys[level] = py - fy; rzs[level] = pz - fz;
        const unsigned gx = (unsigned)fx, gy = (unsigned)fy, gz = (unsigned)fz;

        const unsigned d = gx ^ (gx + 1u);
        gbits[level] = d ^ (d >> 1);                      // 1,2,4,8,...

        const unsigned hy0 = gy * 2654435761u;
        const unsigned hy1 = (gy + 1u) * 2654435761u;
        const unsigned hz0 = gz * 805459861u;
        const unsigned hz1 = (gz + 1u) * 805459861u;
        const unsigned lvl = (unsigned)level << 19;

        const unsigned h0 = (gx ^ hy0 ^ hz0) & HMASK;
        const unsigned h1 = (gx ^ hy1 ^ hz0) & HMASK;
        const unsigned h2 = (gx ^ hy0 ^ hz1) & HMASK;
        const unsigned h3 = (gx ^ hy1 ^ hz1) & HMASK;
        P0[level * 4 + 0] = lvl | (h0 ^ (h0 >> 1));
        P0[level * 4 + 1] = lvl | (h1 ^ (h1 >> 1));
        P0[level * 4 + 2] = lvl | (h2 ^ (h2 >> 1));
        P0[level * 4 + 3] = lvl | (h3 ^ (h3 >> 1));
    }

    // e0 = bx=0 corner value, e1 = bx=1, per (level, yz-combo)
    unsigned e0[12], e1[12];

#pragma unroll
    for (int level = 0; level < 3; ++level) {
        const unsigned g = gbits[level];
        if (g == 1u) {
            // pair adjacent: one aligned 8B load covers both (p=1/2)
#pragma unroll
            for (int j = 0; j < 4; ++j) {
                const unsigned P = P0[level * 4 + j];
                const uintx2 q = *reinterpret_cast<const uintx2*>(tbl + (P & ~1u));
                const unsigned o = P & 1u;
                e0[level * 4 + j] = o ? q.y : q.x;
                e1[level * 4 + j] = o ? q.x : q.y;
            }
        } else if (g == 2u) {
            // pair at distance 2: one aligned 16B quad covers both (p=1/4)
#pragma unroll
            for (int j = 0; j < 4; ++j) {
                const unsigned P = P0[level * 4 + j];
                const uintx4 q = *reinterpret_cast<const uintx4*>(tbl + (P & ~3u));
                const unsigned o = P & 3u;
                e0[level * 4 + j] = sel4(q, o);
                e1[level * 4 + j] = sel4(q, o ^ 2u);
            }
        } else {
            // distant partner: two scalar 4B loads (p=1/4)
#pragma unroll
            for (int j = 0; j < 4; ++j) {
                const unsigned P = P0[level * 4 + j];
                e0[level * 4 + j] = tbl[P];
                e1[level * 4 + j] = tbl[P ^ g];
            }
        }
    }

    float o0 = 0.0f, o1 = 0.0f;
#pragma unroll
    for (int level = 0; level < 3; ++level) {
        const float rx = rxs[level], ry = rys[level], rz = rzs[level];
        const float wx1 = rx, wx0 = 1.0f - rx;
        const float wy1 = ry, wy0 = 1.0f - ry;
        const float wz1 = rz, wz0 = 1.0f - rz;
        const float wyz[4] = { wy0 * wz0, wy1 * wz0, wy0 * wz1, wy1 * wz1 };
#pragma unroll
        for (int j = 0; j < 4; ++j) {
            const __half2 a = *reinterpret_cast<const __half2*>(&e0[level * 4 + j]);
            const __half2 b = *reinterpret_cast<const __half2*>(&e1[level * 4 + j]);
            const float2 fa = __half22float2(a);
            const float2 fb = __half22float2(b);
            const float wA = wx0 * wyz[j], wB = wx1 * wyz[j];
            o0 = fmaf(wA, fa.x, o0); o1 = fmaf(wA, fa.y, o1);
            o0 = fmaf(wB, fb.x, o0); o1 = fmaf(wB, fb.y, o1);
        }
    }

    floatx2 r; r.x = o0; r.y = o1;
    __builtin_nontemporal_store(r, &out[i]);
}

// ---- fallback (R1 kernel) if ws_size is too small for the packed table ----
__global__ __launch_bounds__(256) void grid_fallback_kernel(
    const float* __restrict__ triplane,
    const float* __restrict__ inputs,
    float* __restrict__ out)
{
    const int i = blockIdx.x * blockDim.x + threadIdx.x;
    if (i >= NPOINTS) return;
    const float x0 = (inputs[3 * i + 0] + 1.0f) * 0.5f;
    const float y0 = (inputs[3 * i + 1] + 1.0f) * 0.5f;
    const float z0 = (inputs[3 * i + 2] + 1.0f) * 0.5f;
    float o0 = 0.0f, o1 = 0.0f;
#pragma unroll
    for (int level = 0; level < 3; ++level) {
        const float scale = (float)((128 << level) - 1);
        const float px = fmaf(x0, scale, 0.5f);
        const float py = fmaf(y0, scale, 0.5f);
        const float pz = fmaf(z0, scale, 0.5f);
        const float fx = floorf(px), fy = floorf(py), fz = floorf(pz);
        const float rx = px - fx, ry = py - fy, rz = pz - fz;
        const unsigned gx = (unsigned)fx, gy = (unsigned)fy, gz = (unsigned)fz;
        const float* __restrict__ base = triplane + level * (2 * PLANE);
#pragma unroll
        for (int c = 0; c < 8; ++c) {
            const unsigned bx = (c >> 0) & 1, by = (c >> 1) & 1, bz = (c >> 2) & 1;
            const unsigned h = (gx + bx) ^ ((gy + by) * 2654435761u) ^ ((gz + bz) * 805459861u);
            const unsigned local = h & HMASK;
            const float w = (bx ? rx : 1.0f - rx) * (by ? ry : 1.0f - ry) * (bz ? rz : 1.0f - rz);
            o0 = fmaf(w, base[local], o0);
            o1 = fmaf(w, base[PLANE + local], o1);
        }
    }
    reinterpret_cast<float2*>(out)[i] = make_float2(o0, o1);
}

extern "C" void kernel_launch(void* const* d_in, const int* in_sizes, int n_in,
                              void* d_out, int out_size, void* d_ws, size_t ws_size,
                              hipStream_t stream) {
    const float* triplane = (const float*)d_in[0];  // 3*2*1024*512 fp32
    const float* inputs   = (const float*)d_in[1];  // B*3 fp32
    const int threads = 256;
    const int gblocks = NPOINTS / threads;          // 8192

    if (ws_size >= (size_t)NTAB * sizeof(unsigned)) {
        unsigned* tbl = (unsigned*)d_ws;
        tp_convert_kernel<<<NTAB / threads, threads, 0, stream>>>(triplane, tbl);
        grid_gather_kernel<<<gblocks, threads, 0, stream>>>(tbl, inputs, (floatx2*)d_out);
    } else {
        grid_fallback_kernel<<<gblocks, threads, 0, stream>>>(triplane, inputs, (float*)d_out);
    }
}

// Round 7
// 229.837 us; speedup vs baseline: 1.1222x; 1.0070x over previous
//
#include <hip/hip_runtime.h>
#include <hip/hip_fp16.h>

// GridEncoder (instant-NGP triplane hash grid), static config:
//   D=3, L=3, C=2, base_res=128, per_level_scale=2, hashmap=2^19,
//   align_corners=False, linear interp, B=2^21.
// All levels hash-index; hmap=2^19 -> mod == & 0x7FFFF.
//
// R1: naive fp32 -> 543 us kernel (HBM-bound, FETCH 1.97 GB), 587 total
//     -> fixed harness overhead ~43 us.
// R2: half2 table + 3 level passes -> 254 us (62/pass; 2.27 cyc/4B-req).
// R4: fused 24x4B gathers -> 175 us gather.
// R5: all-16B quads, 15 req/pt -> 184 us. Request-only model falsified.
//     Fit: cost/lane-request ~= 1.65 cyc + 0.12 cyc/byte (all rounds).
// R6: mixed-width Gray loads -> gather 156.6 us (45.9 cyc/pt vs 39 model
//     floor). Total gap 75 us => prepass ~30 us (scatter-write bound?).
// R7: IDENTITY layout. d = gx^(gx+1) = 2^m-1, and XOR by (2^m-1) preserves
//     aligned 2^m windows -> identity already gives the same pair-width
//     distribution as Gray (1/2: 8B, 1/4: 16B, 1/4: 2x4B; 15 req/pt is the
//     floor: no 4-window holds the XOR-7 partner). Drops Gray ALU from the
//     gather AND makes the prepass pure streaming (float4 in, uintx4 out,
//     4 entries/thread) -> prepass ~30 -> ~4 us.

#define NPOINTS  2097152
#define HMASK    0x7FFFFu
#define PLANE    524288            // entries per level table
#define NTAB     (3 * PLANE)       // packed half2 entries (6 MB)

typedef float    floatx2 __attribute__((ext_vector_type(2)));
typedef unsigned uintx2  __attribute__((ext_vector_type(2)));
typedef unsigned uintx4  __attribute__((ext_vector_type(4)));

__device__ __forceinline__ unsigned pack2(float a, float b) {
    const __half2 h2 = __halves2half2(__float2half_rn(a), __float2half_rn(b));
    return *reinterpret_cast<const unsigned*>(&h2);
}

// ---- prepass: tbl[level*2^19 + h] = half2(b[h], b[PLANE+h]) ----
// identity layout -> fully streaming: float4 reads, uintx4 write
__global__ __launch_bounds__(256) void tp_convert_kernel(
    const float* __restrict__ tp, uintx4* __restrict__ tbl)
{
    const unsigned t = blockIdx.x * 256u + threadIdx.x;   // < NTAB/4
    const unsigned level = t >> 17;                       // 2^17 quads/level
    const unsigned i4    = (t & 131071u) << 2;
    const float* __restrict__ b = tp + level * (2u * PLANE);
    const float4 c0 = *reinterpret_cast<const float4*>(b + i4);
    const float4 c1 = *reinterpret_cast<const float4*>(b + PLANE + i4);
    uintx4 o;
    o.x = pack2(c0.x, c1.x);
    o.y = pack2(c0.y, c1.y);
    o.z = pack2(c0.z, c1.z);
    o.w = pack2(c0.w, c1.w);
    tbl[t] = o;   // level*2^19 + i4 == 4*t
}

__device__ __forceinline__ unsigned sel4(uintx4 q, unsigned o) {
    const unsigned a = (o & 1u) ? q.y : q.x;
    const unsigned b = (o & 1u) ? q.w : q.z;
    return (o & 2u) ? b : a;
}

// ---- fused gather, mixed-width pair loads on the identity layout ----
__global__ __launch_bounds__(256) void grid_gather_kernel(
    const unsigned* __restrict__ tbl,
    const float* __restrict__ inputs,
    floatx2* __restrict__ out)
{
    const int i = blockIdx.x * 256 + threadIdx.x;

    const float x = __builtin_nontemporal_load(&inputs[3 * i + 0]);
    const float y = __builtin_nontemporal_load(&inputs[3 * i + 1]);
    const float z = __builtin_nontemporal_load(&inputs[3 * i + 2]);
    const float x0 = (x + 1.0f) * 0.5f;
    const float y0 = (y + 1.0f) * 0.5f;
    const float z0 = (z + 1.0f) * 0.5f;

    unsigned P0[12];        // lvl*2^19 + hash of each bx=0 corner
    unsigned dx[3];         // gx ^ (gx+1) = 2^m - 1, per level
    float rxs[3], rys[3], rzs[3];

#pragma unroll
    for (int level = 0; level < 3; ++level) {
        const float scale = (float)((128 << level) - 1);  // 127, 255, 511
        const float px = fmaf(x0, scale, 0.5f);
        const float py = fmaf(y0, scale, 0.5f);
        const float pz = fmaf(z0, scale, 0.5f);
        const float fx = floorf(px), fy = floorf(py), fz = floorf(pz);
        rxs[level] = px - fx; rys[level] = py - fy; rzs[level] = pz - fz;
        const unsigned gx = (unsigned)fx, gy = (unsigned)fy, gz = (unsigned)fz;

        dx[level] = gx ^ (gx + 1u);                       // 1,3,7,15,...

        const unsigned hy0 = gy * 2654435761u;
        const unsigned hy1 = (gy + 1u) * 2654435761u;
        const unsigned hz0 = gz * 805459861u;
        const unsigned hz1 = (gz + 1u) * 805459861u;
        const unsigned lvl = (unsigned)level << 19;

        P0[level * 4 + 0] = lvl | ((gx ^ hy0 ^ hz0) & HMASK);
        P0[level * 4 + 1] = lvl | ((gx ^ hy1 ^ hz0) & HMASK);
        P0[level * 4 + 2] = lvl | ((gx ^ hy0 ^ hz1) & HMASK);
        P0[level * 4 + 3] = lvl | ((gx ^ hy1 ^ hz1) & HMASK);
    }

    // e0 = bx=0 corner value, e1 = bx=1, per (level, yz-combo)
    unsigned e0[12], e1[12];

#pragma unroll
    for (int level = 0; level < 3; ++level) {
        const unsigned d = dx[level];
        if (d == 1u) {
            // partner adjacent within aligned 8B (p = 1/2)
#pragma unroll
            for (int j = 0; j < 4; ++j) {
                const unsigned P = P0[level * 4 + j];
                const uintx2 q = *reinterpret_cast<const uintx2*>(tbl + (P & ~1u));
                const unsigned o = P & 1u;
                e0[level * 4 + j] = o ? q.y : q.x;
                e1[level * 4 + j] = o ? q.x : q.y;
            }
        } else if (d == 3u) {
            // partner within aligned 16B quad (p = 1/4)
#pragma unroll
            for (int j = 0; j < 4; ++j) {
                const unsigned P = P0[level * 4 + j];
                const uintx4 q = *reinterpret_cast<const uintx4*>(tbl + (P & ~3u));
                const unsigned o = P & 3u;
                e0[level * 4 + j] = sel4(q, o);
                e1[level * 4 + j] = sel4(q, o ^ 3u);
            }
        } else {
            // distant partner: two scalar 4B loads (p = 1/4)
#pragma unroll
            for (int j = 0; j < 4; ++j) {
                const unsigned P = P0[level * 4 + j];
                e0[level * 4 + j] = tbl[P];
                e1[level * 4 + j] = tbl[P ^ d];
            }
        }
    }

    float o0 = 0.0f, o1 = 0.0f;
#pragma unroll
    for (int level = 0; level < 3; ++level) {
        const float rx = rxs[level], ry = rys[level], rz = rzs[level];
        const float wx1 = rx, wx0 = 1.0f - rx;
        const float wy1 = ry, wy0 = 1.0f - ry;
        const float wz1 = rz, wz0 = 1.0f - rz;
        const float wyz[4] = { wy0 * wz0, wy1 * wz0, wy0 * wz1, wy1 * wz1 };
#pragma unroll
        for (int j = 0; j < 4; ++j) {
            const __half2 a = *reinterpret_cast<const __half2*>(&e0[level * 4 + j]);
            const __half2 b = *reinterpret_cast<const __half2*>(&e1[level * 4 + j]);
            const float2 fa = __half22float2(a);
            const float2 fb = __half22float2(b);
            const float wA = wx0 * wyz[j], wB = wx1 * wyz[j];
            o0 = fmaf(wA, fa.x, o0); o1 = fmaf(wA, fa.y, o1);
            o0 = fmaf(wB, fb.x, o0); o1 = fmaf(wB, fb.y, o1);
        }
    }

    floatx2 r; r.x = o0; r.y = o1;
    __builtin_nontemporal_store(r, &out[i]);
}

// ---- fallback (R1 kernel) if ws_size is too small for the packed table ----
__global__ __launch_bounds__(256) void grid_fallback_kernel(
    const float* __restrict__ triplane,
    const float* __restrict__ inputs,
    float* __restrict__ out)
{
    const int i = blockIdx.x * blockDim.x + threadIdx.x;
    if (i >= NPOINTS) return;
    const float x0 = (inputs[3 * i + 0] + 1.0f) * 0.5f;
    const float y0 = (inputs[3 * i + 1] + 1.0f) * 0.5f;
    const float z0 = (inputs[3 * i + 2] + 1.0f) * 0.5f;
    float o0 = 0.0f, o1 = 0.0f;
#pragma unroll
    for (int level = 0; level < 3; ++level) {
        const float scale = (float)((128 << level) - 1);
        const float px = fmaf(x0, scale, 0.5f);
        const float py = fmaf(y0, scale, 0.5f);
        const float pz = fmaf(z0, scale, 0.5f);
        const float fx = floorf(px), fy = floorf(py), fz = floorf(pz);
        const float rx = px - fx, ry = py - fy, rz = pz - fz;
        const unsigned gx = (unsigned)fx, gy = (unsigned)fy, gz = (unsigned)fz;
        const float* __restrict__ base = triplane + level * (2 * PLANE);
#pragma unroll
        for (int c = 0; c < 8; ++c) {
            const unsigned bx = (c >> 0) & 1, by = (c >> 1) & 1, bz = (c >> 2) & 1;
            const unsigned h = (gx + bx) ^ ((gy + by) * 2654435761u) ^ ((gz + bz) * 805459861u);
            const unsigned local = h & HMASK;
            const float w = (bx ? rx : 1.0f - rx) * (by ? ry : 1.0f - ry) * (bz ? rz : 1.0f - rz);
            o0 = fmaf(w, base[local], o0);
            o1 = fmaf(w, base[PLANE + local], o1);
        }
    }
    reinterpret_cast<float2*>(out)[i] = make_float2(o0, o1);
}

extern "C" void kernel_launch(void* const* d_in, const int* in_sizes, int n_in,
                              void* d_out, int out_size, void* d_ws, size_t ws_size,
                              hipStream_t stream) {
    const float* triplane = (const float*)d_in[0];  // 3*2*1024*512 fp32
    const float* inputs   = (const float*)d_in[1];  // B*3 fp32
    const int threads = 256;
    const int gblocks = NPOINTS / threads;          // 8192

    if (ws_size >= (size_t)NTAB * sizeof(unsigned)) {
        unsigned* tbl = (unsigned*)d_ws;
        tp_convert_kernel<<<(NTAB / 4) / threads, threads, 0, stream>>>(
            triplane, (uintx4*)tbl);
        grid_gather_kernel<<<gblocks, threads, 0, stream>>>(tbl, inputs, (floatx2*)d_out);
    } else {
        grid_fallback_kernel<<<gblocks, threads, 0, stream>>>(triplane, inputs, (float*)d_out);
    }
}

// Round 8
// 198.359 us; speedup vs baseline: 1.3003x; 1.1587x over previous
//
#include <hip/hip_runtime.h>
#include <hip/hip_fp16.h>

// GridEncoder (instant-NGP triplane hash grid), static config:
//   D=3, L=3, C=2, base_res=128, per_level_scale=2, hashmap=2^19,
//   align_corners=False, linear interp, B=2^21.
// All levels hash-index; hmap=2^19 -> mod == & 0x7FFFF.
//
// R1: naive fp32 -> kernel 543 us, total 587 -> fixed harness overhead ~43.
// R2: half2 table + 3 level passes -> 62 us/pass @ 8 req/pt = 270 G req/s
//     (2 MB level table L2-resident).
// R4: fused 24x4B -> 175 us (203 G req/s).  R5: all-16B quads -> 184 us.
// R6/R7: mixed-width pair loads (15 req/pt floor for this layout class),
//     identity layout == Gray for x-pairs -> gather 155.7 us, FETCH 474 MB:
//     6 MB table > 4 MiB/XCD L2 -> ~70x re-fetch from L3; fused kernel runs
//     at 203 G req/s vs 270 when L2-resident -> L2-miss penalty, not an
//     intrinsic request floor.
// R8: LEVEL-CLUSTERED fused gather: 2048 blocks (co-resident) x 4 pts/thread,
//     level-major loop + __syncthreads between levels -> active working set
//     = one 2 MB level table at a time (L2-resident), accumulators in regs,
//     inputs read once, no RMW, still 2 dispatches.

#define NPOINTS  2097152
#define HMASK    0x7FFFFu
#define PLANE    524288            // entries per level table
#define NTAB     (3 * PLANE)       // packed half2 entries (6 MB)
#define GBLOCKS  2048
#define TTHREADS (GBLOCKS * 256)   // 524288
#define PPT      4                 // points per thread

typedef float    floatx2 __attribute__((ext_vector_type(2)));
typedef unsigned uintx2  __attribute__((ext_vector_type(2)));
typedef unsigned uintx4  __attribute__((ext_vector_type(4)));

__device__ __forceinline__ unsigned pack2(float a, float b) {
    const __half2 h2 = __halves2half2(__float2half_rn(a), __float2half_rn(b));
    return *reinterpret_cast<const unsigned*>(&h2);
}

// ---- prepass: tbl[level*2^19 + h] = half2(b[h], b[PLANE+h]) ----
__global__ __launch_bounds__(256) void tp_convert_kernel(
    const float* __restrict__ tp, uintx4* __restrict__ tbl)
{
    const unsigned t = blockIdx.x * 256u + threadIdx.x;   // < NTAB/4
    const unsigned level = t >> 17;                       // 2^17 quads/level
    const unsigned i4    = (t & 131071u) << 2;
    const float* __restrict__ b = tp + level * (2u * PLANE);
    const float4 c0 = *reinterpret_cast<const float4*>(b + i4);
    const float4 c1 = *reinterpret_cast<const float4*>(b + PLANE + i4);
    uintx4 o;
    o.x = pack2(c0.x, c1.x);
    o.y = pack2(c0.y, c1.y);
    o.z = pack2(c0.z, c1.z);
    o.w = pack2(c0.w, c1.w);
    tbl[t] = o;
}

__device__ __forceinline__ unsigned sel4(uintx4 q, unsigned o) {
    const unsigned a = (o & 1u) ? q.y : q.x;
    const unsigned b = (o & 1u) ? q.w : q.z;
    return (o & 2u) ? b : a;
}

// ---- level-clustered fused gather ----
__global__ __launch_bounds__(256) void grid_gather_kernel(
    const unsigned* __restrict__ tbl,
    const float* __restrict__ inputs,
    floatx2* __restrict__ out)
{
    const int t = blockIdx.x * 256 + threadIdx.x;

    float x0[PPT], y0[PPT], z0[PPT];
#pragma unroll
    for (int p = 0; p < PPT; ++p) {
        const int i = t + p * TTHREADS;
        const float x = __builtin_nontemporal_load(&inputs[3 * i + 0]);
        const float y = __builtin_nontemporal_load(&inputs[3 * i + 1]);
        const float z = __builtin_nontemporal_load(&inputs[3 * i + 2]);
        x0[p] = (x + 1.0f) * 0.5f;
        y0[p] = (y + 1.0f) * 0.5f;
        z0[p] = (z + 1.0f) * 0.5f;
    }

    float o0[PPT], o1[PPT];
#pragma unroll
    for (int p = 0; p < PPT; ++p) { o0[p] = 0.0f; o1[p] = 0.0f; }

#pragma unroll
    for (int level = 0; level < 3; ++level) {
        const float scale = (float)((128 << level) - 1);  // 127, 255, 511
        const unsigned lvl = (unsigned)level << 19;

#pragma unroll
        for (int p = 0; p < PPT; ++p) {
            const float px = fmaf(x0[p], scale, 0.5f);
            const float py = fmaf(y0[p], scale, 0.5f);
            const float pz = fmaf(z0[p], scale, 0.5f);
            const float fx = floorf(px), fy = floorf(py), fz = floorf(pz);
            const float rx = px - fx, ry = py - fy, rz = pz - fz;
            const unsigned gx = (unsigned)fx, gy = (unsigned)fy, gz = (unsigned)fz;

            const unsigned d = gx ^ (gx + 1u);            // 1,3,7,15,...
            const unsigned hy0 = gy * 2654435761u;
            const unsigned hy1 = (gy + 1u) * 2654435761u;
            const unsigned hz0 = gz * 805459861u;
            const unsigned hz1 = (gz + 1u) * 805459861u;

            unsigned P0[4];
            P0[0] = lvl | ((gx ^ hy0 ^ hz0) & HMASK);
            P0[1] = lvl | ((gx ^ hy1 ^ hz0) & HMASK);
            P0[2] = lvl | ((gx ^ hy0 ^ hz1) & HMASK);
            P0[3] = lvl | ((gx ^ hy1 ^ hz1) & HMASK);

            unsigned e0[4], e1[4];
            if (d == 1u) {
                // partner adjacent within aligned 8B (p = 1/2)
#pragma unroll
                for (int j = 0; j < 4; ++j) {
                    const unsigned P = P0[j];
                    const uintx2 q = *reinterpret_cast<const uintx2*>(tbl + (P & ~1u));
                    const unsigned o = P & 1u;
                    e0[j] = o ? q.y : q.x;
                    e1[j] = o ? q.x : q.y;
                }
            } else if (d == 3u) {
                // partner within aligned 16B quad (p = 1/4)
#pragma unroll
                for (int j = 0; j < 4; ++j) {
                    const unsigned P = P0[j];
                    const uintx4 q = *reinterpret_cast<const uintx4*>(tbl + (P & ~3u));
                    const unsigned o = P & 3u;
                    e0[j] = sel4(q, o);
                    e1[j] = sel4(q, o ^ 3u);
                }
            } else {
                // distant partner: two scalar 4B loads (p = 1/4)
#pragma unroll
                for (int j = 0; j < 4; ++j) {
                    const unsigned P = P0[j];
                    e0[j] = tbl[P];
                    e1[j] = tbl[P ^ d];
                }
            }

            const float wx1 = rx, wx0 = 1.0f - rx;
            const float wy1 = ry, wy0 = 1.0f - ry;
            const float wz1 = rz, wz0 = 1.0f - rz;
            const float wyz[4] = { wy0 * wz0, wy1 * wz0, wy0 * wz1, wy1 * wz1 };
#pragma unroll
            for (int j = 0; j < 4; ++j) {
                const __half2 a = *reinterpret_cast<const __half2*>(&e0[j]);
                const __half2 b = *reinterpret_cast<const __half2*>(&e1[j]);
                const float2 fa = __half22float2(a);
                const float2 fb = __half22float2(b);
                const float wA = wx0 * wyz[j], wB = wx1 * wyz[j];
                o0[p] = fmaf(wA, fa.x, o0[p]); o1[p] = fmaf(wA, fa.y, o1[p]);
                o0[p] = fmaf(wB, fb.x, o0[p]); o1[p] = fmaf(wB, fb.y, o1[p]);
            }
        }
        // phase alignment: keep all resident waves on the same level so the
        // active table working set stays at one 2 MB level (L2-resident)
        __syncthreads();
    }

#pragma unroll
    for (int p = 0; p < PPT; ++p) {
        floatx2 r; r.x = o0[p]; r.y = o1[p];
        __builtin_nontemporal_store(r, &out[t + p * TTHREADS]);
    }
}

// ---- fallback (R1 kernel) if ws_size is too small for the packed table ----
__global__ __launch_bounds__(256) void grid_fallback_kernel(
    const float* __restrict__ triplane,
    const float* __restrict__ inputs,
    float* __restrict__ out)
{
    const int i = blockIdx.x * blockDim.x + threadIdx.x;
    if (i >= NPOINTS) return;
    const float x0 = (inputs[3 * i + 0] + 1.0f) * 0.5f;
    const float y0 = (inputs[3 * i + 1] + 1.0f) * 0.5f;
    const float z0 = (inputs[3 * i + 2] + 1.0f) * 0.5f;
    float o0 = 0.0f, o1 = 0.0f;
#pragma unroll
    for (int level = 0; level < 3; ++level) {
        const float scale = (float)((128 << level) - 1);
        const float px = fmaf(x0, scale, 0.5f);
        const float py = fmaf(y0, scale, 0.5f);
        const float pz = fmaf(z0, scale, 0.5f);
        const float fx = floorf(px), fy = floorf(py), fz = floorf(pz);
        const float rx = px - fx, ry = py - fy, rz = pz - fz;
        const unsigned gx = (unsigned)fx, gy = (unsigned)fy, gz = (unsigned)fz;
        const float* __restrict__ base = triplane + level * (2 * PLANE);
#pragma unroll
        for (int c = 0; c < 8; ++c) {
            const unsigned bx = (c >> 0) & 1, by = (c >> 1) & 1, bz = (c >> 2) & 1;
            const unsigned h = (gx + bx) ^ ((gy + by) * 2654435761u) ^ ((gz + bz) * 805459861u);
            const unsigned local = h & HMASK;
            const float w = (bx ? rx : 1.0f - rx) * (by ? ry : 1.0f - ry) * (bz ? rz : 1.0f - rz);
            o0 = fmaf(w, base[local], o0);
            o1 = fmaf(w, base[PLANE + local], o1);
        }
    }
    reinterpret_cast<float2*>(out)[i] = make_float2(o0, o1);
}

extern "C" void kernel_launch(void* const* d_in, const int* in_sizes, int n_in,
                              void* d_out, int out_size, void* d_ws, size_t ws_size,
                              hipStream_t stream) {
    const float* triplane = (const float*)d_in[0];  // 3*2*1024*512 fp32
    const float* inputs   = (const float*)d_in[1];  // B*3 fp32
    const int threads = 256;

    if (ws_size >= (size_t)NTAB * sizeof(unsigned)) {
        unsigned* tbl = (unsigned*)d_ws;
        tp_convert_kernel<<<(NTAB / 4) / threads, threads, 0, stream>>>(
            triplane, (uintx4*)tbl);
        grid_gather_kernel<<<GBLOCKS, threads, 0, stream>>>(tbl, inputs, (floatx2*)d_out);
    } else {
        grid_fallback_kernel<<<NPOINTS / threads, threads, 0, stream>>>(
            triplane, inputs, (float*)d_out);
    }
}